// Round 3
// baseline (9594.691 us; speedup 1.0000x reference)
//
#include <hip/hip_runtime.h>
#include <math.h>

#define CN 128   // captions
#define INN 128  // images
#define LN 48    // words
#define RN 36    // regions
#define DN 1024  // feature dim
#define TI 4     // images per block tile
#define RT (TI*RN)   // 144
#define EPSF 1e-8f
#define LSM 9.0f
#define LLSE 6.0f

__device__ __forceinline__ float leaky(float x){ return x > 0.f ? x : 0.1f*x; }

typedef const __attribute__((address_space(1))) unsigned int* gp_t;
typedef __attribute__((address_space(3))) unsigned int* lp_t;
__device__ __forceinline__ void gload16(const float* g, float* l) {
  __builtin_amdgcn_global_load_lds((gp_t)g, (lp_t)l, 16, 0, 0);
}

// ---------------- Kernel 1: Gram matrices + norms ----------------
__global__ __launch_bounds__(256) void gram_kernel(
    const float* __restrict__ imgs, const float* __restrict__ caps,
    float* __restrict__ gI, float* __restrict__ nI,
    float* __restrict__ gC, float* __restrict__ nC)
{
  const int b = blockIdx.x, tid = threadIdx.x;
  if (b < INN) {
    const float* base = imgs + (size_t)b*RN*DN;
    for (int p = tid; p < RN*RN; p += 256) {
      const int r = p / RN, s = p % RN;
      const float4* x = (const float4*)(base + r*DN);
      const float4* y = (const float4*)(base + s*DN);
      float acc = 0.f;
      for (int d = 0; d < DN/4; ++d) {
        float4 a = x[d], bb = y[d];
        acc += a.x*bb.x + a.y*bb.y + a.z*bb.z + a.w*bb.w;
      }
      gI[(size_t)b*RN*RN + p] = acc;
    }
    if (tid < RN) {
      const float4* x = (const float4*)(base + tid*DN);
      float acc = 0.f;
      for (int d = 0; d < DN/4; ++d) {
        float4 a = x[d];
        acc += a.x*a.x + a.y*a.y + a.z*a.z + a.w*a.w;
      }
      nI[b*RN + tid] = sqrtf(fmaxf(acc, 1e-16f));
    }
  } else {
    const int c = b - INN;
    const float* base = caps + (size_t)c*LN*DN;
    for (int p = tid; p < LN*LN; p += 256) {
      const int r = p / LN, s = p % LN;
      const float4* x = (const float4*)(base + r*DN);
      const float4* y = (const float4*)(base + s*DN);
      float acc = 0.f;
      for (int d = 0; d < DN/4; ++d) {
        float4 a = x[d], bb = y[d];
        acc += a.x*bb.x + a.y*bb.y + a.z*bb.z + a.w*bb.w;
      }
      gC[(size_t)c*LN*LN + p] = acc;
    }
    if (tid < LN) {
      const float4* x = (const float4*)(base + tid*DN);
      float acc = 0.f;
      for (int d = 0; d < DN/4; ++d) {
        float4 a = x[d];
        acc += a.x*a.x + a.y*a.y + a.z*a.z + a.w*a.w;
      }
      nC[c*LN + tid] = sqrtf(fmaxf(acc, 1e-16f));
    }
  }
}

// ---------------- Kernel 2: dots tile + team-parallel attention ----------------
__global__ __launch_bounds__(256, 2) void main_kernel(
    const float* __restrict__ imgs, const float* __restrict__ caps,
    const int* __restrict__ cap_lens,
    const float* __restrict__ gI, const float* __restrict__ nI,
    const float* __restrict__ gC, const float* __restrict__ nC,
    float* __restrict__ scores)
{
  // LDS: sDots 27840B + sBuf 36864B + small 3456B = ~68.2KB => 2 blocks/CU
  __shared__ __align__(16) float sDots[LN][RT+1];   // 48 x 145 (odd stride: row+col scalar reads conflict-free)
  __shared__ __align__(16) float sBuf[9216];        // staging(6144) | sGi4(6912)+sGc(2304)
  __shared__ float sColInv[TI*RN];   // 144
  __shared__ float sRowInv[TI*LN];   // 192
  __shared__ float sCapN[LN];
  __shared__ float sImgN[TI*RN];
  __shared__ float sEt[TI*LN];
  __shared__ float sEi[TI*RN];

  const int c  = blockIdx.y;
  const int it = blockIdx.x;
  const int tid = threadIdx.x;
  const int wv = tid >> 6;
  const int nw = cap_lens[c];
  const float nwf = (float)nw;

  const float* capBase = caps + (size_t)c*LN*DN;
  const float* imgBase = imgs + (size_t)it*RT*DN;

  // ---------- Phase A: dots[48][144], K-split over thread halves ----------
  const int t128 = tid & 127;
  const int kh   = tid >> 7;      // 0: dd 0-3, 1: dd 4-7 of each tile
  const int lg   = t128 & 7;      // 8 l-groups of 6
  const int rg   = t128 >> 3;     // 16 r-groups of 9

  float acc[6][9];
  #pragma unroll
  for (int j = 0; j < 6; ++j)
    #pragma unroll
    for (int k = 0; k < 9; ++k) acc[j][k] = 0.f;

  for (int d0 = 0; d0 < DN; d0 += 32) {
    __syncthreads();               // previous compute done with staging
    #pragma unroll
    for (int k = 0; k < 6; ++k) {
      const int ch = k*256 + tid;  // chunk id 0..1535 (<384: caps, else imgs)
      const float* src;
      if (ch < 384) {
        const int row = ch >> 3, seg = (ch & 7) ^ (row & 7);
        src = capBase + row*DN + d0 + seg*4;
      } else {
        const int q = ch - 384;
        const int row = q >> 3, seg = (q & 7) ^ (row & 7);
        src = imgBase + (size_t)row*DN + d0 + seg*4;
      }
      gload16(src, sBuf + (k*256 + wv*64)*4);   // wave-uniform LDS base, lane*16 auto
    }
    asm volatile("s_waitcnt vmcnt(0)" ::: "memory");
    __syncthreads();               // staged data visible
    #pragma unroll
    for (int ds = 0; ds < 4; ++ds) {
      const int dd = kh*4 + ds;
      float4 av[6], bv[9];
      #pragma unroll
      for (int j = 0; j < 6; ++j) {
        const int row = lg*6 + j;
        av[j] = *(const float4*)&sBuf[row*32 + ((dd ^ row) & 7)*4];
      }
      #pragma unroll
      for (int kk = 0; kk < 9; ++kk) {
        const int row = rg*9 + kk;
        bv[kk] = *(const float4*)&sBuf[1536 + row*32 + ((dd ^ row) & 7)*4];
      }
      #pragma unroll
      for (int j = 0; j < 6; ++j)
        #pragma unroll
        for (int kk = 0; kk < 9; ++kk)
          acc[j][kk] += av[j].x*bv[kk].x + av[j].y*bv[kk].y
                      + av[j].z*bv[kk].z + av[j].w*bv[kk].w;
    }
  }
  __syncthreads();                 // all sBuf reads done
  float* sGi4 = sBuf;              // [4][36][48] (blocks of 12: 9 valid + 3 zero)
  float* sGc  = sBuf + 6912;       // [48][48]
  if (kh == 1) {
    #pragma unroll
    for (int j = 0; j < 6; ++j)
      #pragma unroll
      for (int kk = 0; kk < 9; ++kk)
        sDots[lg*6+j][rg*9+kk] = acc[j][kk];
  }
  for (int idx = tid; idx < 1728; idx += 256)   // zero sGi4 (pads)
    ((float4*)sGi4)[idx] = make_float4(0.f,0.f,0.f,0.f);
  __syncthreads();                 // kh1 stores + zeros visible
  if (kh == 0) {
    #pragma unroll
    for (int j = 0; j < 6; ++j)
      #pragma unroll
      for (int kk = 0; kk < 9; ++kk)
        sDots[lg*6+j][rg*9+kk] += acc[j][kk];
  }
  // fill Gi (padded col-blocks), Gc, norms
  for (int idx = tid; idx < TI*RN*RN; idx += 256) {
    const int i = idx / (RN*RN), rem = idx - i*(RN*RN);
    const int s = rem / RN, col = rem - s*RN;
    const int blk = col / 9, cib = col - blk*9;
    sGi4[(i*RN + s)*48 + blk*12 + cib] = gI[(size_t)(it*TI+i)*RN*RN + rem];
  }
  for (int idx = tid; idx < 576; idx += 256) {
    const int rw = idx/12, mq = idx - rw*12;
    *(float4*)&sGc[rw*48 + mq*4] =
      *(const float4*)(gC + (size_t)c*LN*LN + rw*LN + mq*4);
  }
  if (tid < LN) sCapN[tid] = nC[c*LN + tid];
  if (tid < TI*RN) sImgN[tid] = nI[it*TI*RN + tid];
  __syncthreads();                 // sDots final, fills visible
  if (tid < TI*RN) {               // colInv per (i, region)
    const int i = tid/RN, r = tid - i*RN;
    float s = 0.f;
    for (int l = 0; l < LN; ++l) { const float v = leaky(sDots[l][i*RN+r]); s += v*v; }
    sColInv[tid] = 1.f/(sqrtf(s) + EPSF);
  }
  if (tid < TI*LN) {               // rowInv per (i, word)
    const int i = tid/LN, l = tid - i*LN;
    float s = 0.f;
    for (int r = 0; r < RN; ++r) { const float v = leaky(sDots[l][i*RN+r]); s += v*v; }
    sRowInv[tid] = 1.f/(sqrtf(s) + EPSF);
  }
  __syncthreads();

  // ---------- Phase B: 4-lane teams, one (row, image) each ----------
  const int team = tid >> 2, q4 = tid & 3;

  // ===== t2i: 192 rows (i*48+l), lane owns 9 regions (padded to 12) =====
  #pragma unroll 1
  for (int pass = 0; pass < 3; ++pass) {
    const int rowid = pass*64 + team;
    const int i = rowid / LN, l = rowid - i*LN;
    const int cb = i*RN + q4*9;
    float d9[9], x12[12];
    #pragma unroll
    for (int j = 0; j < 9; ++j) d9[j] = sDots[l][cb + j];
    float m = -1e30f;
    #pragma unroll
    for (int j = 0; j < 9; ++j) {
      const float v = leaky(d9[j]) * sColInv[cb + j] * LSM;
      x12[j] = v; m = fmaxf(m, v);
    }
    x12[9] = x12[10] = x12[11] = -1e30f;
    m = fmaxf(m, __shfl_xor(m, 1, 4));
    m = fmaxf(m, __shfl_xor(m, 2, 4));
    float se = 0.f;
    #pragma unroll
    for (int j = 0; j < 12; ++j) { const float e = expf(x12[j] - m); x12[j] = e; se += e; }
    se += __shfl_xor(se, 1, 4); se += __shfl_xor(se, 2, 4);
    float s = 0.f;
    #pragma unroll
    for (int j = 0; j < 12; ++j) { const float p = x12[j]/se; x12[j] = p; s += p; }
    s += __shfl_xor(s, 1, 4); s += __shfl_xor(s, 2, 4);
    float ts = 0.f;
    #pragma unroll
    for (int j = 0; j < 12; ++j) {
      const float tv = (x12[j]*36.f - s > 0.f) ? x12[j] : 0.f;
      x12[j] = tv; ts += tv;
    }
    ts += __shfl_xor(ts, 1, 4); ts += __shfl_xor(ts, 2, 4);
    const float den = (ts > 0.f) ? ts : 1.f;
    float w12 = 0.f;
    #pragma unroll
    for (int j = 0; j < 9; ++j) w12 += x12[j]*d9[j];
    w12 += __shfl_xor(w12, 1, 4); w12 += __shfl_xor(w12, 2, 4);
    // qq = x^T Gi x, folded (no hm[] array): broadcast x_s, each lane dots its 12-col block
    float qq = 0.f;
    const float* giB = sGi4 + (size_t)i*RN*48 + q4*12;
    #pragma unroll
    for (int sl = 0; sl < 4; ++sl) {
      #pragma unroll
      for (int si = 0; si < 9; ++si) {
        const float tv = __shfl(x12[si], sl, 4);
        const float4* gr = (const float4*)(giB + (sl*9 + si)*48);
        const float4 g0 = gr[0], g1 = gr[1], g2 = gr[2];
        const float p =
          x12[0]*g0.x + x12[1]*g0.y + x12[2]*g0.z + x12[3]*g0.w +
          x12[4]*g1.x + x12[5]*g1.y + x12[6]*g1.z + x12[7]*g1.w +
          x12[8]*g2.x + x12[9]*g2.y + x12[10]*g2.z + x12[11]*g2.w;
        qq += tv * p;
      }
    }
    qq += __shfl_xor(qq, 1, 4); qq += __shfl_xor(qq, 2, 4);
    if (q4 == 0) {
      const float w2 = sqrtf(fmaxf(qq/(den*den), 1e-16f));
      const float sim = (w12/den) / fmaxf(sCapN[l]*w2, EPSF);
      sEt[rowid] = (l < nw) ? expf(LLSE*sim) : 0.f;
    }
  }

  // ===== i2t: 144 rows (i*36+r), lane owns 12 words =====
  #pragma unroll 1
  for (int pass = 0; pass < 3; ++pass) {
    const int rowid = pass*64 + team;
    if (rowid < TI*RN) {
      const int i = rowid / RN, r = rowid - i*RN;
      float d12[12], x12[12];
      #pragma unroll
      for (int j = 0; j < 12; ++j) d12[j] = sDots[q4*12+j][i*RN + r];
      float m = -1e30f;
      #pragma unroll
      for (int j = 0; j < 12; ++j) {
        const int l = q4*12 + j;
        const float v = (l < nw) ? leaky(d12[j]) * sRowInv[i*LN + l] * LSM : -1e9f;
        x12[j] = v; m = fmaxf(m, v);
      }
      m = fmaxf(m, __shfl_xor(m, 1, 4));
      m = fmaxf(m, __shfl_xor(m, 2, 4));
      float se = 0.f;
      #pragma unroll
      for (int j = 0; j < 12; ++j) { const float e = expf(x12[j] - m); x12[j] = e; se += e; }
      se += __shfl_xor(se, 1, 4); se += __shfl_xor(se, 2, 4);
      float s = 0.f;
      #pragma unroll
      for (int j = 0; j < 12; ++j) { const float p = x12[j]/se; x12[j] = p; s += p; }
      s += __shfl_xor(s, 1, 4); s += __shfl_xor(s, 2, 4);
      float ts = 0.f;
      #pragma unroll
      for (int j = 0; j < 12; ++j) {
        const float tv = (x12[j]*nwf - s > 0.f) ? x12[j] : 0.f;
        x12[j] = tv; ts += tv;
      }
      ts += __shfl_xor(ts, 1, 4); ts += __shfl_xor(ts, 2, 4);
      const float den = (ts > 0.f) ? ts : 1.f;
      float w12 = 0.f;
      #pragma unroll
      for (int j = 0; j < 12; ++j) w12 += x12[j]*d12[j];
      w12 += __shfl_xor(w12, 1, 4); w12 += __shfl_xor(w12, 2, 4);
      float qq = 0.f;
      const float* gcB = sGc + q4*12;
      #pragma unroll
      for (int sl = 0; sl < 4; ++sl) {
        #pragma unroll
        for (int si = 0; si < 12; ++si) {
          const float tv = __shfl(x12[si], sl, 4);
          const float4* gr = (const float4*)(gcB + (sl*12 + si)*48);
          const float4 g0 = gr[0], g1 = gr[1], g2 = gr[2];
          const float p =
            x12[0]*g0.x + x12[1]*g0.y + x12[2]*g0.z + x12[3]*g0.w +
            x12[4]*g1.x + x12[5]*g1.y + x12[6]*g1.z + x12[7]*g1.w +
            x12[8]*g2.x + x12[9]*g2.y + x12[10]*g2.z + x12[11]*g2.w;
          qq += tv * p;
        }
      }
      qq += __shfl_xor(qq, 1, 4); qq += __shfl_xor(qq, 2, 4);
      if (q4 == 0) {
        const float w2 = sqrtf(fmaxf(qq/(den*den), 1e-16f));
        const float sim = (w12/den) / fmaxf(sImgN[rowid]*w2, EPSF);
        sEi[rowid] = expf(LLSE*sim);
      }
    }
  }
  __syncthreads();
  if (tid < TI) {
    float st = 0.f, si2 = 0.f;
    for (int l = 0; l < LN; ++l) st += sEt[tid*LN + l];
    for (int r = 0; r < RN; ++r) si2 += sEi[tid*RN + r];
    scores[(size_t)(it*TI + tid)*CN + c] = logf(st)/LLSE + logf(si2)/LLSE;
  }
}

// ---------------- Kernel 3: margin ranking loss ----------------
__global__ __launch_bounds__(128) void loss_kernel(
    const float* __restrict__ S, float* __restrict__ out)
{
  __shared__ float red[128];
  const int t = threadIdx.x;
  const float d = S[t*CN + t];
  float m1 = -1e30f, m2 = -1e30f;
  for (int cc = 0; cc < CN; ++cc)
    if (cc != t) m1 = fmaxf(m1, 0.2f + S[t*CN+cc] - d);
  for (int i2 = 0; i2 < INN; ++i2)
    if (i2 != t) m2 = fmaxf(m2, 0.2f + S[i2*CN+t] - d);
  red[t] = fmaxf(m1, 0.f) + fmaxf(m2, 0.f);
  __syncthreads();
  for (int s = 64; s > 0; s >>= 1) {
    if (t < s) red[t] += red[t+s];
    __syncthreads();
  }
  if (t == 0) out[0] = red[0];
}

extern "C" void kernel_launch(void* const* d_in, const int* in_sizes, int n_in,
                              void* d_out, int out_size, void* d_ws, size_t ws_size,
                              hipStream_t stream) {
  (void)in_sizes; (void)n_in; (void)out_size; (void)ws_size;
  const float* imgs = (const float*)d_in[0];
  const float* caps = (const float*)d_in[1];
  const int*   lens = (const int*)d_in[2];
  float* ws = (float*)d_ws;
  float* gI = ws;                         // 128*36*36
  float* nI = gI + (size_t)INN*RN*RN;
  float* gC = nI + (size_t)INN*RN;        // 128*48*48
  float* nC = gC + (size_t)CN*LN*LN;
  float* scores = nC + (size_t)CN*LN;     // 128*128

  gram_kernel<<<dim3(INN+CN), dim3(256), 0, stream>>>(imgs, caps, gI, nI, gC, nC);
  main_kernel<<<dim3(INN/TI, CN), dim3(256), 0, stream>>>(
      imgs, caps, lens, gI, nI, gC, nC, scores);
  loss_kernel<<<dim3(1), dim3(128), 0, stream>>>(scores, (float*)d_out);
}

// Round 4
// 1469.557 us; speedup vs baseline: 6.5290x; 6.5290x over previous
//
#include <hip/hip_runtime.h>
#include <math.h>

#define CN 128   // captions
#define INN 128  // images
#define LN 48    // words
#define RN 36    // regions
#define DN 1024  // feature dim
#define TI 4     // images per attn block tile
#define RT 144   // TI*RN
#define MT 6144  // CN*LN
#define NT 4608  // INN*RN
#define STL 132  // LDS stride for transposed GEMM tiles
#define EPSF 1e-8f
#define LSM 9.0f
#define LLSE 6.0f

__device__ __forceinline__ float leaky(float x){ return x > 0.f ? x : 0.1f*x; }

// ---------------- Kernel 1: Gram matrices + norms ----------------
__global__ __launch_bounds__(256) void gram_kernel(
    const float* __restrict__ imgs, const float* __restrict__ caps,
    float* __restrict__ gI, float* __restrict__ nI,
    float* __restrict__ gC, float* __restrict__ nC)
{
  const int b = blockIdx.x, tid = threadIdx.x;
  if (b < INN) {
    const float* base = imgs + (size_t)b*RN*DN;
    for (int p = tid; p < RN*RN; p += 256) {
      const int r = p / RN, s = p % RN;
      const float4* x = (const float4*)(base + r*DN);
      const float4* y = (const float4*)(base + s*DN);
      float acc = 0.f;
      for (int d = 0; d < DN/4; ++d) {
        float4 a = x[d], bb = y[d];
        acc += a.x*bb.x + a.y*bb.y + a.z*bb.z + a.w*bb.w;
      }
      gI[(size_t)b*RN*RN + p] = acc;
    }
    if (tid < RN) {
      const float4* x = (const float4*)(base + tid*DN);
      float acc = 0.f;
      for (int d = 0; d < DN/4; ++d) {
        float4 a = x[d];
        acc += a.x*a.x + a.y*a.y + a.z*a.z + a.w*a.w;
      }
      nI[b*RN + tid] = sqrtf(fmaxf(acc, 1e-16f));
    }
  } else {
    const int c = b - INN;
    const float* base = caps + (size_t)c*LN*DN;
    for (int p = tid; p < LN*LN; p += 256) {
      const int r = p / LN, s = p % LN;
      const float4* x = (const float4*)(base + r*DN);
      const float4* y = (const float4*)(base + s*DN);
      float acc = 0.f;
      for (int d = 0; d < DN/4; ++d) {
        float4 a = x[d], bb = y[d];
        acc += a.x*bb.x + a.y*bb.y + a.z*bb.z + a.w*bb.w;
      }
      gC[(size_t)c*LN*LN + p] = acc;
    }
    if (tid < LN) {
      const float4* x = (const float4*)(base + tid*DN);
      float acc = 0.f;
      for (int d = 0; d < DN/4; ++d) {
        float4 a = x[d];
        acc += a.x*a.x + a.y*a.y + a.z*a.z + a.w*a.w;
      }
      nC[c*LN + tid] = sqrtf(fmaxf(acc, 1e-16f));
    }
  }
}

// ---------------- Kernel 2: dots GEMM  C[m][n] = caps_flat[m]·imgs_flat[n] ----------------
// M rows are captions*48 within the current chunk (cbase), N = 4608 image-regions.
__global__ __launch_bounds__(256) void dots_gemm(
    const float* __restrict__ caps, const float* __restrict__ imgs,
    float* __restrict__ dots, int cbase, int mlim)
{
  __shared__ __align__(16) float As[16*STL];
  __shared__ __align__(16) float Bs[16*STL];
  const int tid = threadIdx.x;
  const int M0 = blockIdx.y * 128;     // row offset within chunk
  const int N0 = blockIdx.x * 128;
  const int tx = tid & 15, ty = tid >> 4;
  const int srow = tid >> 1;           // 0..127 staged row
  const int sk   = (tid & 1) * 8;      // k start within 16-tile (8 floats)

  int arow = cbase*LN + M0 + srow;     // global caption-word row
  if (arow >= MT) arow = MT - 1;       // clamp (partial last tile); store is guarded
  const float* Ag = caps + (size_t)arow*DN + sk;
  const float* Bg = imgs + ((size_t)N0 + srow)*DN + sk;

  float4 ra0 = *(const float4*)(Ag);
  float4 ra1 = *(const float4*)(Ag + 4);
  float4 rb0 = *(const float4*)(Bg);
  float4 rb1 = *(const float4*)(Bg + 4);

  float acc[8][8];
  #pragma unroll
  for (int j = 0; j < 8; ++j)
    #pragma unroll
    for (int k = 0; k < 8; ++k) acc[j][k] = 0.f;

  for (int t = 0; t < DN/16; ++t) {
    __syncthreads();                   // previous tile's readers done
    #pragma unroll
    for (int e = 0; e < 4; ++e) {      // transposed store As[k][m], 2-way max conflict
      As[(sk+e)*STL + srow]     = ((const float*)&ra0)[e];
      As[(sk+4+e)*STL + srow]   = ((const float*)&ra1)[e];
      Bs[(sk+e)*STL + srow]     = ((const float*)&rb0)[e];
      Bs[(sk+4+e)*STL + srow]   = ((const float*)&rb1)[e];
    }
    __syncthreads();
    if (t < DN/16 - 1) {               // prefetch next tile into regs (hides HBM/L3 latency)
      const float* An = Ag + (t+1)*16;
      const float* Bn = Bg + (t+1)*16;
      ra0 = *(const float4*)(An);  ra1 = *(const float4*)(An + 4);
      rb0 = *(const float4*)(Bn);  rb1 = *(const float4*)(Bn + 4);
    }
    #pragma unroll
    for (int kk = 0; kk < 16; ++kk) {
      const float4 a0 = *(const float4*)&As[kk*STL + ty*8];
      const float4 a1 = *(const float4*)&As[kk*STL + ty*8 + 4];
      const float4 b0 = *(const float4*)&Bs[kk*STL + tx*8];
      const float4 b1 = *(const float4*)&Bs[kk*STL + tx*8 + 4];
      const float av[8] = {a0.x,a0.y,a0.z,a0.w,a1.x,a1.y,a1.z,a1.w};
      const float bv[8] = {b0.x,b0.y,b0.z,b0.w,b1.x,b1.y,b1.z,b1.w};
      #pragma unroll
      for (int j = 0; j < 8; ++j)
        #pragma unroll
        for (int k = 0; k < 8; ++k)
          acc[j][k] += av[j]*bv[k];
    }
  }
  #pragma unroll
  for (int j = 0; j < 8; ++j) {
    const int mloc = M0 + ty*8 + j;
    if (mloc < mlim) {
      float* crow = dots + (size_t)mloc*NT + N0 + tx*8;
      *(float4*)(crow)     = make_float4(acc[j][0],acc[j][1],acc[j][2],acc[j][3]);
      *(float4*)(crow + 4) = make_float4(acc[j][4],acc[j][5],acc[j][6],acc[j][7]);
    }
  }
}

// ---------------- Kernel 3: attention + scores ----------------
__global__ __launch_bounds__(256) void attn_kernel(
    const float* __restrict__ dots, const int* __restrict__ cap_lens,
    const float* __restrict__ gI, const float* __restrict__ nI,
    const float* __restrict__ gC, const float* __restrict__ nC,
    float* __restrict__ scores, int cbase)
{
  __shared__ float sDots[LN][RT+1];                 // 48 x 145
  __shared__ __align__(16) float sGi4[TI*RN*48];    // [4][36][48], col-blocks of 12 (9 valid + 3 zero)
  __shared__ __align__(16) float sGc[LN*48];        // [48][48]
  __shared__ float sColInv[TI*RN];
  __shared__ float sRowInv[TI*LN];
  __shared__ float sCapN[LN];
  __shared__ float sImgN[TI*RN];
  __shared__ float sEt[TI*LN];
  __shared__ float sEi[TI*RN];

  const int cl = blockIdx.y;            // local caption index within chunk
  const int c  = cbase + cl;
  const int it = blockIdx.x;
  const int tid = threadIdx.x;
  const int nw = cap_lens[c];
  const float nwf = (float)nw;

  // load dots tile (48 x 144) — global float4 coalesced, scalar LDS stores (stride 145)
  for (int idx = tid; idx < LN*RT/4; idx += 256) {
    const int l = idx / 36, jseg = idx - l*36;
    const float4 v = *(const float4*)(dots + ((size_t)cl*LN + l)*NT + (size_t)it*RT + jseg*4);
    float* dst = &sDots[l][jseg*4];
    dst[0]=v.x; dst[1]=v.y; dst[2]=v.z; dst[3]=v.w;
  }
  // zero sGi4 (pads), fill Gc, norms
  for (int idx = tid; idx < TI*RN*48/4; idx += 256)
    ((float4*)sGi4)[idx] = make_float4(0.f,0.f,0.f,0.f);
  for (int idx = tid; idx < 576; idx += 256) {
    const int rw = idx/12, mq = idx - rw*12;
    *(float4*)&sGc[rw*48 + mq*4] = *(const float4*)(gC + (size_t)c*LN*LN + rw*LN + mq*4);
  }
  if (tid < LN) sCapN[tid] = nC[c*LN + tid];
  if (tid < TI*RN) sImgN[tid] = nI[it*TI*RN + tid];
  __syncthreads();

  // fill Gi valid entries; colInv/rowInv from sDots
  for (int idx = tid; idx < TI*RN*RN; idx += 256) {
    const int i = idx / (RN*RN), rem = idx - i*(RN*RN);
    const int s = rem / RN, col = rem - s*RN;
    const int blk = col / 9, cib = col - blk*9;
    sGi4[(i*RN + s)*48 + blk*12 + cib] = gI[(size_t)(it*TI+i)*RN*RN + rem];
  }
  if (tid < TI*RN) {
    const int i = tid/RN, r = tid - i*RN;
    float s = 0.f;
    for (int l = 0; l < LN; ++l) { const float v = leaky(sDots[l][i*RN+r]); s += v*v; }
    sColInv[tid] = 1.f/(sqrtf(s) + EPSF);
  }
  if (tid < TI*LN) {
    const int i = tid/LN, l = tid - i*LN;
    float s = 0.f;
    for (int r = 0; r < RN; ++r) { const float v = leaky(sDots[l][i*RN+r]); s += v*v; }
    sRowInv[tid] = 1.f/(sqrtf(s) + EPSF);
  }
  __syncthreads();

  const int team = tid >> 2, q4 = tid & 3;

  // ===== t2i: 192 rows (i*48+l), lane owns 9 regions (padded to 12) =====
  #pragma unroll 1
  for (int pass = 0; pass < 3; ++pass) {
    const int rowid = pass*64 + team;
    const int i = rowid / LN, l = rowid - i*LN;
    const int cb = i*RN + q4*9;
    float d9[9], x12[12];
    #pragma unroll
    for (int j = 0; j < 9; ++j) d9[j] = sDots[l][cb + j];
    float m = -1e30f;
    #pragma unroll
    for (int j = 0; j < 9; ++j) {
      const float v = leaky(d9[j]) * sColInv[cb + j] * LSM;
      x12[j] = v; m = fmaxf(m, v);
    }
    x12[9] = x12[10] = x12[11] = -1e30f;
    m = fmaxf(m, __shfl_xor(m, 1, 4));
    m = fmaxf(m, __shfl_xor(m, 2, 4));
    float se = 0.f;
    #pragma unroll
    for (int j = 0; j < 12; ++j) { const float e = expf(x12[j] - m); x12[j] = e; se += e; }
    se += __shfl_xor(se, 1, 4); se += __shfl_xor(se, 2, 4);
    float s = 0.f;
    #pragma unroll
    for (int j = 0; j < 12; ++j) { const float p = x12[j]/se; x12[j] = p; s += p; }
    s += __shfl_xor(s, 1, 4); s += __shfl_xor(s, 2, 4);
    float ts = 0.f;
    #pragma unroll
    for (int j = 0; j < 12; ++j) {
      const float tv = (x12[j]*36.f - s > 0.f) ? x12[j] : 0.f;
      x12[j] = tv; ts += tv;
    }
    ts += __shfl_xor(ts, 1, 4); ts += __shfl_xor(ts, 2, 4);
    const float den = (ts > 0.f) ? ts : 1.f;
    float w12 = 0.f;
    #pragma unroll
    for (int j = 0; j < 9; ++j) w12 += x12[j]*d9[j];
    w12 += __shfl_xor(w12, 1, 4); w12 += __shfl_xor(w12, 2, 4);
    float qq = 0.f;
    const float* giB = sGi4 + (size_t)i*RN*48 + q4*12;
    #pragma unroll
    for (int sl = 0; sl < 4; ++sl) {
      #pragma unroll
      for (int si = 0; si < 9; ++si) {
        const float tv = __shfl(x12[si], sl, 4);
        const float4* gr = (const float4*)(giB + (sl*9 + si)*48);
        const float4 g0 = gr[0], g1 = gr[1], g2 = gr[2];
        const float p =
          x12[0]*g0.x + x12[1]*g0.y + x12[2]*g0.z + x12[3]*g0.w +
          x12[4]*g1.x + x12[5]*g1.y + x12[6]*g1.z + x12[7]*g1.w +
          x12[8]*g2.x + x12[9]*g2.y + x12[10]*g2.z + x12[11]*g2.w;
        qq += tv * p;
      }
    }
    qq += __shfl_xor(qq, 1, 4); qq += __shfl_xor(qq, 2, 4);
    if (q4 == 0) {
      const float w2 = sqrtf(fmaxf(qq/(den*den), 1e-16f));
      const float sim = (w12/den) / fmaxf(sCapN[l]*w2, EPSF);
      sEt[rowid] = (l < nw) ? expf(LLSE*sim) : 0.f;
    }
  }

  // ===== i2t: 144 rows (i*36+r), lane owns 12 words =====
  #pragma unroll 1
  for (int pass = 0; pass < 3; ++pass) {
    const int rowid = pass*64 + team;
    if (rowid < TI*RN) {
      const int i = rowid / RN, r = rowid - i*RN;
      float d12[12], x12[12];
      #pragma unroll
      for (int j = 0; j < 12; ++j) d12[j] = sDots[q4*12+j][i*RN + r];
      float m = -1e30f;
      #pragma unroll
      for (int j = 0; j < 12; ++j) {
        const int l = q4*12 + j;
        const float v = (l < nw) ? leaky(d12[j]) * sRowInv[i*LN + l] * LSM : -1e9f;
        x12[j] = v; m = fmaxf(m, v);
      }
      m = fmaxf(m, __shfl_xor(m, 1, 4));
      m = fmaxf(m, __shfl_xor(m, 2, 4));
      float se = 0.f;
      #pragma unroll
      for (int j = 0; j < 12; ++j) { const float e = expf(x12[j] - m); x12[j] = e; se += e; }
      se += __shfl_xor(se, 1, 4); se += __shfl_xor(se, 2, 4);
      float s = 0.f;
      #pragma unroll
      for (int j = 0; j < 12; ++j) { const float p = x12[j]/se; x12[j] = p; s += p; }
      s += __shfl_xor(s, 1, 4); s += __shfl_xor(s, 2, 4);
      float ts = 0.f;
      #pragma unroll
      for (int j = 0; j < 12; ++j) {
        const float tv = (x12[j]*nwf - s > 0.f) ? x12[j] : 0.f;
        x12[j] = tv; ts += tv;
      }
      ts += __shfl_xor(ts, 1, 4); ts += __shfl_xor(ts, 2, 4);
      const float den = (ts > 0.f) ? ts : 1.f;
      float w12 = 0.f;
      #pragma unroll
      for (int j = 0; j < 12; ++j) w12 += x12[j]*d12[j];
      w12 += __shfl_xor(w12, 1, 4); w12 += __shfl_xor(w12, 2, 4);
      float qq = 0.f;
      const float* gcB = sGc + q4*12;
      #pragma unroll
      for (int sl = 0; sl < 4; ++sl) {
        #pragma unroll
        for (int si = 0; si < 12; ++si) {
          const float tv = __shfl(x12[si], sl, 4);
          const float4* gr = (const float4*)(gcB + (sl*12 + si)*48);
          const float4 g0 = gr[0], g1 = gr[1], g2 = gr[2];
          const float p =
            x12[0]*g0.x + x12[1]*g0.y + x12[2]*g0.z + x12[3]*g0.w +
            x12[4]*g1.x + x12[5]*g1.y + x12[6]*g1.z + x12[7]*g1.w +
            x12[8]*g2.x + x12[9]*g2.y + x12[10]*g2.z + x12[11]*g2.w;
          qq += tv * p;
        }
      }
      qq += __shfl_xor(qq, 1, 4); qq += __shfl_xor(qq, 2, 4);
      if (q4 == 0) {
        const float w2 = sqrtf(fmaxf(qq/(den*den), 1e-16f));
        const float sim = (w12/den) / fmaxf(sImgN[rowid]*w2, EPSF);
        sEi[rowid] = expf(LLSE*sim);
      }
    }
  }
  __syncthreads();
  if (tid < TI) {
    float st = 0.f, si2 = 0.f;
    for (int l = 0; l < LN; ++l) st += sEt[tid*LN + l];
    for (int r = 0; r < RN; ++r) si2 += sEi[tid*RN + r];
    scores[(size_t)(it*TI + tid)*CN + c] = logf(st)/LLSE + logf(si2)/LLSE;
  }
}

// ---------------- Kernel 4: margin ranking loss ----------------
__global__ __launch_bounds__(128) void loss_kernel(
    const float* __restrict__ S, float* __restrict__ out)
{
  __shared__ float red[128];
  const int t = threadIdx.x;
  const float d = S[t*CN + t];
  float m1 = -1e30f, m2 = -1e30f;
  for (int cc = 0; cc < CN; ++cc)
    if (cc != t) m1 = fmaxf(m1, 0.2f + S[t*CN+cc] - d);
  for (int i2 = 0; i2 < INN; ++i2)
    if (i2 != t) m2 = fmaxf(m2, 0.2f + S[i2*CN+t] - d);
  red[t] = fmaxf(m1, 0.f) + fmaxf(m2, 0.f);
  __syncthreads();
  for (int s = 64; s > 0; s >>= 1) {
    if (t < s) red[t] += red[t+s];
    __syncthreads();
  }
  if (t == 0) out[0] = red[0];
}

extern "C" void kernel_launch(void* const* d_in, const int* in_sizes, int n_in,
                              void* d_out, int out_size, void* d_ws, size_t ws_size,
                              hipStream_t stream) {
  (void)in_sizes; (void)n_in; (void)out_size;
  const float* imgs = (const float*)d_in[0];
  const float* caps = (const float*)d_in[1];
  const int*   lens = (const int*)d_in[2];

  const size_t smallF = (size_t)INN*RN*RN + INN*RN + (size_t)CN*LN*LN + CN*LN + (size_t)INN*CN;
  int g = CN;                               // captions per chunk
  while (g > 2) {
    const size_t need = ((size_t)g*LN*NT + smallF) * 4;
    if (need <= ws_size) break;
    g >>= 1;
  }

  float* ws = (float*)d_ws;
  float* dots   = ws;
  float* gI     = dots + (size_t)g*LN*NT;
  float* nI     = gI + (size_t)INN*RN*RN;
  float* gC     = nI + (size_t)INN*RN;
  float* nC     = gC + (size_t)CN*LN*LN;
  float* scores = nC + (size_t)CN*LN;

  gram_kernel<<<dim3(INN+CN), dim3(256), 0, stream>>>(imgs, caps, gI, nI, gC, nC);
  const int mtiles = (g*LN + 127) / 128;
  for (int c0 = 0; c0 < CN; c0 += g) {
    dots_gemm<<<dim3(NT/128, mtiles), dim3(256), 0, stream>>>(caps, imgs, dots, c0, g*LN);
    attn_kernel<<<dim3(INN/TI, g), dim3(256), 0, stream>>>(
        dots, lens, gI, nI, gC, nC, scores, c0);
  }
  loss_kernel<<<dim3(1), dim3(128), 0, stream>>>(scores, (float*)d_out);
}

// Round 5
// 843.387 us; speedup vs baseline: 11.3764x; 1.7424x over previous
//
#include <hip/hip_runtime.h>
#include <math.h>

#define CN 128   // captions
#define INN 128  // images
#define LN 48    // words
#define RN 36    // regions
#define DN 1024  // feature dim
#define TI 4     // images per attn block tile
#define RT 144   // TI*RN
#define MT 6144  // CN*LN
#define NT 4608  // INN*RN
#define EPSF 1e-8f
#define LSM 9.0f
#define LLSE 6.0f

__device__ __forceinline__ float leaky(float x){ return x > 0.f ? x : 0.1f*x; }

typedef const __attribute__((address_space(1))) unsigned int* gp_t;
typedef __attribute__((address_space(3))) unsigned int* lp_t;
__device__ __forceinline__ void gload16u(const ushort* g, ushort* l) {
  __builtin_amdgcn_global_load_lds((gp_t)g, (lp_t)l, 16, 0, 0);
}

typedef short s16x8 __attribute__((ext_vector_type(8)));
typedef float f32x4 __attribute__((ext_vector_type(4)));

// ---------------- Kernel 0: fp32 -> bf16 hi/lo split (RNE) ----------------
__global__ __launch_bounds__(256) void conv_kernel(
    const float* __restrict__ caps, const float* __restrict__ imgs,
    ushort* __restrict__ aHi, ushort* __restrict__ aLo,
    ushort* __restrict__ bHi, ushort* __restrict__ bLo)
{
  const int NA = MT*DN/4, NB = NT*DN/4;
  for (int i = blockIdx.x*256 + threadIdx.x; i < NA + NB; i += gridDim.x*256) {
    const float4 v = (i < NA) ? ((const float4*)caps)[i] : ((const float4*)imgs)[i - NA];
    const float fv[4] = {v.x, v.y, v.z, v.w};
    ushort hh[4], ll[4];
    #pragma unroll
    for (int e = 0; e < 4; ++e) {
      const unsigned u = __float_as_uint(fv[e]);
      const ushort hi = (ushort)((u + 0x7fffu + ((u>>16)&1u)) >> 16);
      const float res = fv[e] - __uint_as_float((unsigned)hi << 16);
      const unsigned u2 = __float_as_uint(res);
      hh[e] = hi;
      ll[e] = (ushort)((u2 + 0x7fffu + ((u2>>16)&1u)) >> 16);
    }
    const ushort4 h = make_ushort4(hh[0],hh[1],hh[2],hh[3]);
    const ushort4 lo = make_ushort4(ll[0],ll[1],ll[2],ll[3]);
    if (i < NA) { ((ushort4*)aHi)[i] = h;    ((ushort4*)aLo)[i] = lo; }
    else        { ((ushort4*)bHi)[i-NA] = h; ((ushort4*)bLo)[i-NA] = lo; }
  }
}

// ---------------- Kernel 1: Gram matrices + norms (fp32) ----------------
__global__ __launch_bounds__(256) void gram_kernel(
    const float* __restrict__ imgs, const float* __restrict__ caps,
    float* __restrict__ gI, float* __restrict__ nI,
    float* __restrict__ gC, float* __restrict__ nC)
{
  const int b = blockIdx.x, tid = threadIdx.x;
  if (b < INN) {
    const float* base = imgs + (size_t)b*RN*DN;
    for (int p = tid; p < RN*RN; p += 256) {
      const int r = p / RN, s = p % RN;
      const float4* x = (const float4*)(base + r*DN);
      const float4* y = (const float4*)(base + s*DN);
      float acc = 0.f;
      for (int d = 0; d < DN/4; ++d) {
        float4 a = x[d], bb = y[d];
        acc += a.x*bb.x + a.y*bb.y + a.z*bb.z + a.w*bb.w;
      }
      gI[(size_t)b*RN*RN + p] = acc;
    }
    if (tid < RN) {
      const float4* x = (const float4*)(base + tid*DN);
      float acc = 0.f;
      for (int d = 0; d < DN/4; ++d) {
        float4 a = x[d];
        acc += a.x*a.x + a.y*a.y + a.z*a.z + a.w*a.w;
      }
      nI[b*RN + tid] = sqrtf(fmaxf(acc, 1e-16f));
    }
  } else {
    const int c = b - INN;
    const float* base = caps + (size_t)c*LN*DN;
    for (int p = tid; p < LN*LN; p += 256) {
      const int r = p / LN, s = p % LN;
      const float4* x = (const float4*)(base + r*DN);
      const float4* y = (const float4*)(base + s*DN);
      float acc = 0.f;
      for (int d = 0; d < DN/4; ++d) {
        float4 a = x[d], bb = y[d];
        acc += a.x*bb.x + a.y*bb.y + a.z*bb.z + a.w*bb.w;
      }
      gC[(size_t)c*LN*LN + p] = acc;
    }
    if (tid < LN) {
      const float4* x = (const float4*)(base + tid*DN);
      float acc = 0.f;
      for (int d = 0; d < DN/4; ++d) {
        float4 a = x[d];
        acc += a.x*a.x + a.y*a.y + a.z*a.z + a.w*a.w;
      }
      nC[c*LN + tid] = sqrtf(fmaxf(acc, 1e-16f));
    }
  }
}

// ---------------- Kernel 2: dots GEMM via bf16x3 MFMA ----------------
// C[m][n] = sum_k caps[m][k]*imgs[n][k], m in chunk rows, n = 4608.
// 128x128 tile, BK=32, 4 waves each 64x64 (4x4 frags of 16x16x32).
// LDS linear; global source pre-swizzled g' = g ^ ((row>>1)&3) so frag
// ds_read_b128 at 64B row stride is ~2-way (free).
__global__ __launch_bounds__(256) void dots_gemm_mfma(
    const ushort* __restrict__ aHi, const ushort* __restrict__ aLo,
    const ushort* __restrict__ bHi, const ushort* __restrict__ bLo,
    float* __restrict__ dots, int arow0)
{
  __shared__ __align__(16) ushort sT[16384];   // Ah[0,8K)B Al[8,16K) Bh[16,24K) Bl[24,32K)
  const int tid = threadIdx.x;
  const int wv = tid >> 6, lane = tid & 63;
  const int l15 = lane & 15, kg = lane >> 4;
  const int wr = wv >> 1, wc = wv & 1;
  const int M0 = blockIdx.y * 128;     // chunk-local row offset
  const int N0 = blockIdx.x * 128;

  // frag LDS offsets (ushort units) — constant across K-steps
  int offA[4], offB[4];
  #pragma unroll
  for (int f = 0; f < 4; ++f) {
    const int rA = wr*64 + f*16 + l15;
    offA[f] = rA*32 + ((kg ^ ((rA>>1)&3)) << 3);
    const int rB = wc*64 + f*16 + l15;
    offB[f] = rB*32 + ((kg ^ ((rB>>1)&3)) << 3);
  }
  // staging assignment: chunk ch = h*256 + wv*64 + lane (2 halves)
  int srow[2], sgk[2]; unsigned dOff[2];
  #pragma unroll
  for (int h = 0; h < 2; ++h) {
    const int ch = h*256 + wv*64 + lane;
    const int row = ch >> 2, gp = ch & 3;
    srow[h] = row;
    sgk[h] = (gp ^ ((row>>1)&3)) * 8;
    dOff[h] = (unsigned)(h*256 + wv*64) * 8;   // wave-uniform ushort offset
  }

  f32x4 acc[4][4];
  #pragma unroll
  for (int mf = 0; mf < 4; ++mf)
    #pragma unroll
    for (int nf = 0; nf < 4; ++nf) acc[mf][nf] = (f32x4){0.f,0.f,0.f,0.f};

  const size_t aR = (size_t)(arow0 + M0);
  for (int k0 = 0; k0 < DN; k0 += 32) {
    __syncthreads();                       // prev tile's readers done
    #pragma unroll
    for (int h = 0; h < 2; ++h) {
      const size_t ao = (aR + srow[h])*DN + k0 + sgk[h];
      const size_t bo = ((size_t)(N0 + srow[h]))*DN + k0 + sgk[h];
      gload16u(aHi + ao, sT + dOff[h]);
      gload16u(aLo + ao, sT + 4096 + dOff[h]);
      gload16u(bHi + bo, sT + 8192 + dOff[h]);
      gload16u(bLo + bo, sT + 12288 + dOff[h]);
    }
    asm volatile("s_waitcnt vmcnt(0)" ::: "memory");
    __syncthreads();                       // staged data visible
    s16x8 ah[4], al[4], bh[4], bl[4];
    #pragma unroll
    for (int f = 0; f < 4; ++f) {
      ah[f] = *(const s16x8*)&sT[offA[f]];
      al[f] = *(const s16x8*)&sT[4096 + offA[f]];
      bh[f] = *(const s16x8*)&sT[8192 + offB[f]];
      bl[f] = *(const s16x8*)&sT[12288 + offB[f]];
    }
    #pragma unroll
    for (int mf = 0; mf < 4; ++mf)
      #pragma unroll
      for (int nf = 0; nf < 4; ++nf) {
        acc[mf][nf] = __builtin_amdgcn_mfma_f32_16x16x32_bf16(ah[mf], bh[nf], acc[mf][nf], 0,0,0);
        acc[mf][nf] = __builtin_amdgcn_mfma_f32_16x16x32_bf16(ah[mf], bl[nf], acc[mf][nf], 0,0,0);
        acc[mf][nf] = __builtin_amdgcn_mfma_f32_16x16x32_bf16(al[mf], bh[nf], acc[mf][nf], 0,0,0);
      }
  }
  // epilogue: C/D map col=lane&15, row=(lane>>4)*4+reg (m89-verified)
  #pragma unroll
  for (int mf = 0; mf < 4; ++mf)
    #pragma unroll
    for (int nf = 0; nf < 4; ++nf) {
      const int n = N0 + wc*64 + nf*16 + l15;
      #pragma unroll
      for (int r = 0; r < 4; ++r) {
        const int m = M0 + wr*64 + mf*16 + kg*4 + r;
        dots[(size_t)m*NT + n] = acc[mf][nf][r];
      }
    }
}

// ---------------- Kernel 3: attention + scores ----------------
__global__ __launch_bounds__(256) void attn_kernel(
    const float* __restrict__ dots, const int* __restrict__ cap_lens,
    const float* __restrict__ gI, const float* __restrict__ nI,
    const float* __restrict__ gC, const float* __restrict__ nC,
    float* __restrict__ scores, int cbase)
{
  __shared__ float sDots[LN][RT+1];                 // 48 x 145
  __shared__ __align__(16) float sGi4[TI*RN*48];    // [4][36][48], col-blocks of 12 (9 valid + 3 zero)
  __shared__ __align__(16) float sGc[LN*48];        // [48][48]
  __shared__ float sColInv[TI*RN];
  __shared__ float sRowInv[TI*LN];
  __shared__ float sCapN[LN];
  __shared__ float sImgN[TI*RN];
  __shared__ float sEt[TI*LN];
  __shared__ float sEi[TI*RN];

  const int cl = blockIdx.y;            // local caption index within chunk
  const int c  = cbase + cl;
  const int it = blockIdx.x;
  const int tid = threadIdx.x;
  const int nw = cap_lens[c];
  const float nwf = (float)nw;

  for (int idx = tid; idx < LN*RT/4; idx += 256) {
    const int l = idx / 36, jseg = idx - l*36;
    const float4 v = *(const float4*)(dots + ((size_t)cl*LN + l)*NT + (size_t)it*RT + jseg*4);
    float* dst = &sDots[l][jseg*4];
    dst[0]=v.x; dst[1]=v.y; dst[2]=v.z; dst[3]=v.w;
  }
  for (int idx = tid; idx < TI*RN*48/4; idx += 256)
    ((float4*)sGi4)[idx] = make_float4(0.f,0.f,0.f,0.f);
  for (int idx = tid; idx < 576; idx += 256) {
    const int rw = idx/12, mq = idx - rw*12;
    *(float4*)&sGc[rw*48 + mq*4] = *(const float4*)(gC + (size_t)c*LN*LN + rw*LN + mq*4);
  }
  if (tid < LN) sCapN[tid] = nC[c*LN + tid];
  if (tid < TI*RN) sImgN[tid] = nI[it*TI*RN + tid];
  __syncthreads();

  for (int idx = tid; idx < TI*RN*RN; idx += 256) {
    const int i = idx / (RN*RN), rem = idx - i*(RN*RN);
    const int s = rem / RN, col = rem - s*RN;
    const int blk = col / 9, cib = col - blk*9;
    sGi4[(i*RN + s)*48 + blk*12 + cib] = gI[(size_t)(it*TI+i)*RN*RN + rem];
  }
  if (tid < TI*RN) {
    const int i = tid/RN, r = tid - i*RN;
    float s = 0.f;
    for (int l = 0; l < LN; ++l) { const float v = leaky(sDots[l][i*RN+r]); s += v*v; }
    sColInv[tid] = 1.f/(sqrtf(s) + EPSF);
  }
  if (tid < TI*LN) {
    const int i = tid/LN, l = tid - i*LN;
    float s = 0.f;
    for (int r = 0; r < RN; ++r) { const float v = leaky(sDots[l][i*RN+r]); s += v*v; }
    sRowInv[tid] = 1.f/(sqrtf(s) + EPSF);
  }
  __syncthreads();

  const int team = tid >> 2, q4 = tid & 3;

  // ===== t2i =====
  #pragma unroll 1
  for (int pass = 0; pass < 3; ++pass) {
    const int rowid = pass*64 + team;
    const int i = rowid / LN, l = rowid - i*LN;
    const int cb = i*RN + q4*9;
    float d9[9], x12[12];
    #pragma unroll
    for (int j = 0; j < 9; ++j) d9[j] = sDots[l][cb + j];
    float m = -1e30f;
    #pragma unroll
    for (int j = 0; j < 9; ++j) {
      const float v = leaky(d9[j]) * sColInv[cb + j] * LSM;
      x12[j] = v; m = fmaxf(m, v);
    }
    x12[9] = x12[10] = x12[11] = -1e30f;
    m = fmaxf(m, __shfl_xor(m, 1, 4));
    m = fmaxf(m, __shfl_xor(m, 2, 4));
    float se = 0.f;
    #pragma unroll
    for (int j = 0; j < 12; ++j) { const float e = expf(x12[j] - m); x12[j] = e; se += e; }
    se += __shfl_xor(se, 1, 4); se += __shfl_xor(se, 2, 4);
    float s = 0.f;
    #pragma unroll
    for (int j = 0; j < 12; ++j) { const float p = x12[j]/se; x12[j] = p; s += p; }
    s += __shfl_xor(s, 1, 4); s += __shfl_xor(s, 2, 4);
    float ts = 0.f;
    #pragma unroll
    for (int j = 0; j < 12; ++j) {
      const float tv = (x12[j]*36.f - s > 0.f) ? x12[j] : 0.f;
      x12[j] = tv; ts += tv;
    }
    ts += __shfl_xor(ts, 1, 4); ts += __shfl_xor(ts, 2, 4);
    const float den = (ts > 0.f) ? ts : 1.f;
    float w12 = 0.f;
    #pragma unroll
    for (int j = 0; j < 9; ++j) w12 += x12[j]*d9[j];
    w12 += __shfl_xor(w12, 1, 4); w12 += __shfl_xor(w12, 2, 4);
    float qq = 0.f;
    const float* giB = sGi4 + (size_t)i*RN*48 + q4*12;
    #pragma unroll
    for (int sl = 0; sl < 4; ++sl) {
      #pragma unroll
      for (int si = 0; si < 9; ++si) {
        const float tv = __shfl(x12[si], sl, 4);
        const float4* gr = (const float4*)(giB + (sl*9 + si)*48);
        const float4 g0 = gr[0], g1 = gr[1], g2 = gr[2];
        const float p =
          x12[0]*g0.x + x12[1]*g0.y + x12[2]*g0.z + x12[3]*g0.w +
          x12[4]*g1.x + x12[5]*g1.y + x12[6]*g1.z + x12[7]*g1.w +
          x12[8]*g2.x + x12[9]*g2.y + x12[10]*g2.z + x12[11]*g2.w;
        qq += tv * p;
      }
    }
    qq += __shfl_xor(qq, 1, 4); qq += __shfl_xor(qq, 2, 4);
    if (q4 == 0) {
      const float w2 = sqrtf(fmaxf(qq/(den*den), 1e-16f));
      const float sim = (w12/den) / fmaxf(sCapN[l]*w2, EPSF);
      sEt[rowid] = (l < nw) ? expf(LLSE*sim) : 0.f;
    }
  }

  // ===== i2t =====
  #pragma unroll 1
  for (int pass = 0; pass < 3; ++pass) {
    const int rowid = pass*64 + team;
    if (rowid < TI*RN) {
      const int i = rowid / RN, r = rowid - i*RN;
      float d12[12], x12[12];
      #pragma unroll
      for (int j = 0; j < 12; ++j) d12[j] = sDots[q4*12+j][i*RN + r];
      float m = -1e30f;
      #pragma unroll
      for (int j = 0; j < 12; ++j) {
        const int l = q4*12 + j;
        const float v = (l < nw) ? leaky(d12[j]) * sRowInv[i*LN + l] * LSM : -1e9f;
        x12[j] = v; m = fmaxf(m, v);
      }
      m = fmaxf(m, __shfl_xor(m, 1, 4));
      m = fmaxf(m, __shfl_xor(m, 2, 4));
      float se = 0.f;
      #pragma unroll
      for (int j = 0; j < 12; ++j) { const float e = expf(x12[j] - m); x12[j] = e; se += e; }
      se += __shfl_xor(se, 1, 4); se += __shfl_xor(se, 2, 4);
      float s = 0.f;
      #pragma unroll
      for (int j = 0; j < 12; ++j) { const float p = x12[j]/se; x12[j] = p; s += p; }
      s += __shfl_xor(s, 1, 4); s += __shfl_xor(s, 2, 4);
      float ts = 0.f;
      #pragma unroll
      for (int j = 0; j < 12; ++j) {
        const float tv = (x12[j]*nwf - s > 0.f) ? x12[j] : 0.f;
        x12[j] = tv; ts += tv;
      }
      ts += __shfl_xor(ts, 1, 4); ts += __shfl_xor(ts, 2, 4);
      const float den = (ts > 0.f) ? ts : 1.f;
      float w12 = 0.f;
      #pragma unroll
      for (int j = 0; j < 12; ++j) w12 += x12[j]*d12[j];
      w12 += __shfl_xor(w12, 1, 4); w12 += __shfl_xor(w12, 2, 4);
      float qq = 0.f;
      const float* gcB = sGc + q4*12;
      #pragma unroll
      for (int sl = 0; sl < 4; ++sl) {
        #pragma unroll
        for (int si = 0; si < 12; ++si) {
          const float tv = __shfl(x12[si], sl, 4);
          const float4* gr = (const float4*)(gcB + (sl*12 + si)*48);
          const float4 g0 = gr[0], g1 = gr[1], g2 = gr[2];
          const float p =
            x12[0]*g0.x + x12[1]*g0.y + x12[2]*g0.z + x12[3]*g0.w +
            x12[4]*g1.x + x12[5]*g1.y + x12[6]*g1.z + x12[7]*g1.w +
            x12[8]*g2.x + x12[9]*g2.y + x12[10]*g2.z + x12[11]*g2.w;
          qq += tv * p;
        }
      }
      qq += __shfl_xor(qq, 1, 4); qq += __shfl_xor(qq, 2, 4);
      if (q4 == 0) {
        const float w2 = sqrtf(fmaxf(qq/(den*den), 1e-16f));
        const float sim = (w12/den) / fmaxf(sImgN[rowid]*w2, EPSF);
        sEi[rowid] = expf(LLSE*sim);
      }
    }
  }
  __syncthreads();
  if (tid < TI) {
    float st = 0.f, si2 = 0.f;
    for (int l = 0; l < LN; ++l) st += sEt[tid*LN + l];
    for (int r = 0; r < RN; ++r) si2 += sEi[tid*RN + r];
    scores[(size_t)(it*TI + tid)*CN + c] = logf(st)/LLSE + logf(si2)/LLSE;
  }
}

// ---------------- Kernel 4: margin ranking loss ----------------
__global__ __launch_bounds__(128) void loss_kernel(
    const float* __restrict__ S, float* __restrict__ out)
{
  __shared__ float red[128];
  const int t = threadIdx.x;
  const float d = S[t*CN + t];
  float m1 = -1e30f, m2 = -1e30f;
  for (int cc = 0; cc < CN; ++cc)
    if (cc != t) m1 = fmaxf(m1, 0.2f + S[t*CN+cc] - d);
  for (int i2 = 0; i2 < INN; ++i2)
    if (i2 != t) m2 = fmaxf(m2, 0.2f + S[i2*CN+t] - d);
  red[t] = fmaxf(m1, 0.f) + fmaxf(m2, 0.f);
  __syncthreads();
  for (int s = 64; s > 0; s >>= 1) {
    if (t < s) red[t] += red[t+s];
    __syncthreads();
  }
  if (t == 0) out[0] = red[0];
}

extern "C" void kernel_launch(void* const* d_in, const int* in_sizes, int n_in,
                              void* d_out, int out_size, void* d_ws, size_t ws_size,
                              hipStream_t stream) {
  (void)in_sizes; (void)n_in; (void)out_size;
  const float* imgs = (const float*)d_in[0];
  const float* caps = (const float*)d_in[1];
  const int*   lens = (const int*)d_in[2];

  // workspace: [bf16 hi/lo planes][grams/norms/scores][dots chunk]
  const size_t bfUS = 2*((size_t)MT + NT)*DN;   // ushort count, 44.04 MB
  const size_t smallF = (size_t)INN*RN*RN + INN*RN + (size_t)CN*LN*LN + CN*LN + (size_t)INN*CN;
  int g = CN;                                   // captions per chunk (keep g*48 % 128 == 0)
  while (g > 8) {
    const size_t need = bfUS*2 + (smallF + (size_t)g*LN*NT)*4;
    if (need <= ws_size) break;
    g >>= 1;
  }

  ushort* aHi = (ushort*)d_ws;                  // [MT][DN]
  ushort* aLo = aHi + (size_t)MT*DN;
  ushort* bHi = aLo + (size_t)MT*DN;            // [NT][DN]
  ushort* bLo = bHi + (size_t)NT*DN;
  float* fbase = (float*)(bLo + (size_t)NT*DN);
  float* gI     = fbase;
  float* nI     = gI + (size_t)INN*RN*RN;
  float* gC     = nI + (size_t)INN*RN;
  float* nC     = gC + (size_t)CN*LN*LN;
  float* scores = nC + (size_t)CN*LN;
  float* dots   = scores + (size_t)INN*CN;

  conv_kernel<<<dim3(1024), dim3(256), 0, stream>>>(caps, imgs, aHi, aLo, bHi, bLo);
  gram_kernel<<<dim3(INN+CN), dim3(256), 0, stream>>>(imgs, caps, gI, nI, gC, nC);
  for (int c0 = 0; c0 < CN; c0 += g) {
    dots_gemm_mfma<<<dim3(NT/128, g*LN/128), dim3(256), 0, stream>>>(
        aHi, aLo, bHi, bLo, dots, c0*LN);
    attn_kernel<<<dim3(INN/TI, g), dim3(256), 0, stream>>>(
        dots, lens, gI, nI, gC, nC, scores, c0);
  }
  loss_kernel<<<dim3(1), dim3(128), 0, stream>>>(scores, (float*)d_out);
}

// Round 7
// 544.043 us; speedup vs baseline: 17.6359x; 1.5502x over previous
//
#include <hip/hip_runtime.h>
#include <math.h>

#define CN 128   // captions
#define INN 128  // images
#define LN 48    // words
#define RN 36    // regions
#define DN 1024  // feature dim
#define TI 4     // images per attn block tile
#define RT 144   // TI*RN
#define MT 6144  // CN*LN
#define NT 4608  // INN*RN
#define EPSF 1e-8f
#define LSM 9.0f
#define LLSE 6.0f

__device__ __forceinline__ float leaky(float x){ return x > 0.f ? x : 0.1f*x; }
__device__ __forceinline__ float dot4(float4 a, float4 b){
  return a.x*b.x + a.y*b.y + a.z*b.z + a.w*b.w;
}

typedef const __attribute__((address_space(1))) unsigned int* gp_t;
typedef __attribute__((address_space(3))) unsigned int* lp_t;
__device__ __forceinline__ void gload16u(const ushort* g, ushort* l) {
  __builtin_amdgcn_global_load_lds((gp_t)g, (lp_t)l, 16, 0, 0);
}

typedef short s16x8 __attribute__((ext_vector_type(8)));
typedef float f32x4 __attribute__((ext_vector_type(4)));

// ---------------- Kernel 0: fp32 -> bf16 hi/lo split (RNE) ----------------
__global__ __launch_bounds__(256) void conv_kernel(
    const float* __restrict__ caps, const float* __restrict__ imgs,
    ushort* __restrict__ aHi, ushort* __restrict__ aLo,
    ushort* __restrict__ bHi, ushort* __restrict__ bLo)
{
  const int NA = MT*DN/4, NB = NT*DN/4;
  for (int i = blockIdx.x*256 + threadIdx.x; i < NA + NB; i += gridDim.x*256) {
    const float4 v = (i < NA) ? ((const float4*)caps)[i] : ((const float4*)imgs)[i - NA];
    const float fv[4] = {v.x, v.y, v.z, v.w};
    ushort hh[4], ll[4];
    #pragma unroll
    for (int e = 0; e < 4; ++e) {
      const unsigned u = __float_as_uint(fv[e]);
      const ushort hi = (ushort)((u + 0x7fffu + ((u>>16)&1u)) >> 16);
      const float res = fv[e] - __uint_as_float((unsigned)hi << 16);
      const unsigned u2 = __float_as_uint(res);
      hh[e] = hi;
      ll[e] = (ushort)((u2 + 0x7fffu + ((u2>>16)&1u)) >> 16);
    }
    const ushort4 h = make_ushort4(hh[0],hh[1],hh[2],hh[3]);
    const ushort4 lo = make_ushort4(ll[0],ll[1],ll[2],ll[3]);
    if (i < NA) { ((ushort4*)aHi)[i] = h;    ((ushort4*)aLo)[i] = lo; }
    else        { ((ushort4*)bHi)[i-NA] = h; ((ushort4*)bLo)[i-NA] = lo; }
  }
}

// ---------------- Kernel 1: Gram matrices + norms (fp32, LDS D-tiled) ----------------
// One block per image (b<INN) or caption (b>=INN). D staged in 128-wide LDS tiles;
// each thread owns a 2x3 (img) / 3x3 (cap) register tile of row pairs.
// Diagonal/norm writes: EXHAUSTIVE r==s loop (R6 bug: manual case list missed
// (u=0,v=1),(u=0,v=2) -> stale nI -> NaN scores).
__global__ __launch_bounds__(256) void gram_kernel(
    const float* __restrict__ imgs, const float* __restrict__ caps,
    float* __restrict__ gI, float* __restrict__ nI,
    float* __restrict__ gC, float* __restrict__ nC)
{
  __shared__ __align__(16) float L[LN*132];   // max 48 rows x 132
  const int b = blockIdx.x, tid = threadIdx.x;
  if (b < INN) {
    const float* base = imgs + (size_t)b*RN*DN;
    const int rg = tid/12, cg = tid - (tid/12)*12;   // 18x12 teams, 216 active
    const bool active = tid < 216;
    float a[2][3];
    #pragma unroll
    for (int u = 0; u < 2; ++u)
      #pragma unroll
      for (int v = 0; v < 3; ++v) a[u][v] = 0.f;
    for (int d0 = 0; d0 < DN; d0 += 128) {
      __syncthreads();
      for (int idx = tid; idx < RN*32; idx += 256) {
        const int row = idx >> 5, ch = idx & 31;
        *(float4*)&L[row*132 + ch*4] = *(const float4*)(base + row*DN + d0 + ch*4);
      }
      __syncthreads();
      if (active) {
        const float* r0 = &L[(2*rg)*132],   * r1 = &L[(2*rg+1)*132];
        const float* c0 = &L[(3*cg)*132],   * c1 = &L[(3*cg+1)*132], * c2 = &L[(3*cg+2)*132];
        #pragma unroll
        for (int k = 0; k < 32; ++k) {
          const float4 x0 = *(const float4*)(r0 + k*4);
          const float4 x1 = *(const float4*)(r1 + k*4);
          const float4 y0 = *(const float4*)(c0 + k*4);
          const float4 y1 = *(const float4*)(c1 + k*4);
          const float4 y2 = *(const float4*)(c2 + k*4);
          a[0][0] += dot4(x0,y0); a[0][1] += dot4(x0,y1); a[0][2] += dot4(x0,y2);
          a[1][0] += dot4(x1,y0); a[1][1] += dot4(x1,y1); a[1][2] += dot4(x1,y2);
        }
      }
    }
    if (active) {
      float* gb = gI + (size_t)b*RN*RN;
      #pragma unroll
      for (int u = 0; u < 2; ++u)
        #pragma unroll
        for (int v = 0; v < 3; ++v) {
          const int r = 2*rg + u, s = 3*cg + v;
          gb[r*RN + s] = a[u][v];
          if (r == s) nI[b*RN + r] = sqrtf(fmaxf(a[u][v], 1e-16f));
        }
    }
  } else {
    const int c = b - INN;
    const float* base = caps + (size_t)c*LN*DN;
    const int rg = tid >> 4, cg = tid & 15;          // 16x16 teams, all 256 active
    float a[3][3];
    #pragma unroll
    for (int u = 0; u < 3; ++u)
      #pragma unroll
      for (int v = 0; v < 3; ++v) a[u][v] = 0.f;
    for (int d0 = 0; d0 < DN; d0 += 128) {
      __syncthreads();
      for (int idx = tid; idx < LN*32; idx += 256) {
        const int row = idx >> 5, ch = idx & 31;
        *(float4*)&L[row*132 + ch*4] = *(const float4*)(base + row*DN + d0 + ch*4);
      }
      __syncthreads();
      const float* r0 = &L[(3*rg)*132],   * r1 = &L[(3*rg+1)*132], * r2 = &L[(3*rg+2)*132];
      const float* c0 = &L[(3*cg)*132],   * c1 = &L[(3*cg+1)*132], * c2 = &L[(3*cg+2)*132];
      #pragma unroll
      for (int k = 0; k < 32; ++k) {
        const float4 x0 = *(const float4*)(r0 + k*4);
        const float4 x1 = *(const float4*)(r1 + k*4);
        const float4 x2 = *(const float4*)(r2 + k*4);
        const float4 y0 = *(const float4*)(c0 + k*4);
        const float4 y1 = *(const float4*)(c1 + k*4);
        const float4 y2 = *(const float4*)(c2 + k*4);
        a[0][0] += dot4(x0,y0); a[0][1] += dot4(x0,y1); a[0][2] += dot4(x0,y2);
        a[1][0] += dot4(x1,y0); a[1][1] += dot4(x1,y1); a[1][2] += dot4(x1,y2);
        a[2][0] += dot4(x2,y0); a[2][1] += dot4(x2,y1); a[2][2] += dot4(x2,y2);
      }
    }
    float* gb = gC + (size_t)c*LN*LN;
    #pragma unroll
    for (int u = 0; u < 3; ++u)
      #pragma unroll
      for (int v = 0; v < 3; ++v) {
        const int r = 3*rg + u, s = 3*cg + v;
        gb[r*LN + s] = a[u][v];
        if (r == s) nC[c*LN + r] = sqrtf(fmaxf(a[u][v], 1e-16f));
      }
  }
}

// ---------------- Kernel 2: dots GEMM via bf16x3 MFMA ----------------
__global__ __launch_bounds__(256) void dots_gemm_mfma(
    const ushort* __restrict__ aHi, const ushort* __restrict__ aLo,
    const ushort* __restrict__ bHi, const ushort* __restrict__ bLo,
    float* __restrict__ dots, int arow0)
{
  __shared__ __align__(16) ushort sT[16384];   // Ah Al Bh Bl, 8KB each
  const int tid = threadIdx.x;
  const int wv = tid >> 6, lane = tid & 63;
  const int l15 = lane & 15, kg = lane >> 4;
  const int wr = wv >> 1, wc = wv & 1;
  const int M0 = blockIdx.y * 128;
  const int N0 = blockIdx.x * 128;

  int offA[4], offB[4];
  #pragma unroll
  for (int f = 0; f < 4; ++f) {
    const int rA = wr*64 + f*16 + l15;
    offA[f] = rA*32 + ((kg ^ ((rA>>1)&3)) << 3);
    const int rB = wc*64 + f*16 + l15;
    offB[f] = rB*32 + ((kg ^ ((rB>>1)&3)) << 3);
  }
  int srow[2], sgk[2]; unsigned dOff[2];
  #pragma unroll
  for (int h = 0; h < 2; ++h) {
    const int ch = h*256 + wv*64 + lane;
    const int row = ch >> 2, gp = ch & 3;
    srow[h] = row;
    sgk[h] = (gp ^ ((row>>1)&3)) * 8;
    dOff[h] = (unsigned)(h*256 + wv*64) * 8;
  }

  f32x4 acc[4][4];
  #pragma unroll
  for (int mf = 0; mf < 4; ++mf)
    #pragma unroll
    for (int nf = 0; nf < 4; ++nf) acc[mf][nf] = (f32x4){0.f,0.f,0.f,0.f};

  const size_t aR = (size_t)(arow0 + M0);
  for (int k0 = 0; k0 < DN; k0 += 32) {
    __syncthreads();
    #pragma unroll
    for (int h = 0; h < 2; ++h) {
      const size_t ao = (aR + srow[h])*DN + k0 + sgk[h];
      const size_t bo = ((size_t)(N0 + srow[h]))*DN + k0 + sgk[h];
      gload16u(aHi + ao, sT + dOff[h]);
      gload16u(aLo + ao, sT + 4096 + dOff[h]);
      gload16u(bHi + bo, sT + 8192 + dOff[h]);
      gload16u(bLo + bo, sT + 12288 + dOff[h]);
    }
    asm volatile("s_waitcnt vmcnt(0)" ::: "memory");
    __syncthreads();
    s16x8 ah[4], al[4], bh[4], bl[4];
    #pragma unroll
    for (int f = 0; f < 4; ++f) {
      ah[f] = *(const s16x8*)&sT[offA[f]];
      al[f] = *(const s16x8*)&sT[4096 + offA[f]];
      bh[f] = *(const s16x8*)&sT[8192 + offB[f]];
      bl[f] = *(const s16x8*)&sT[12288 + offB[f]];
    }
    #pragma unroll
    for (int mf = 0; mf < 4; ++mf)
      #pragma unroll
      for (int nf = 0; nf < 4; ++nf) {
        acc[mf][nf] = __builtin_amdgcn_mfma_f32_16x16x32_bf16(ah[mf], bh[nf], acc[mf][nf], 0,0,0);
        acc[mf][nf] = __builtin_amdgcn_mfma_f32_16x16x32_bf16(ah[mf], bl[nf], acc[mf][nf], 0,0,0);
        acc[mf][nf] = __builtin_amdgcn_mfma_f32_16x16x32_bf16(al[mf], bh[nf], acc[mf][nf], 0,0,0);
      }
  }
  #pragma unroll
  for (int mf = 0; mf < 4; ++mf)
    #pragma unroll
    for (int nf = 0; nf < 4; ++nf) {
      const int n = N0 + wc*64 + nf*16 + l15;
      #pragma unroll
      for (int r = 0; r < 4; ++r) {
        const int m = M0 + wr*64 + mf*16 + kg*4 + r;
        dots[(size_t)m*NT + n] = acc[mf][nf][r];
      }
    }
}

// ---------------- Kernel 3: attention + scores ----------------
__global__ __launch_bounds__(256) void attn_kernel(
    const float* __restrict__ dots, const int* __restrict__ cap_lens,
    const float* __restrict__ gI, const float* __restrict__ nI,
    const float* __restrict__ gC, const float* __restrict__ nC,
    float* __restrict__ scores, int cbase)
{
  __shared__ float sDots[LN][RT+1];
  __shared__ __align__(16) float sGi4[TI*RN*48];
  __shared__ __align__(16) float sGc[LN*48];
  __shared__ float sColInv[TI*RN];
  __shared__ float sRowInv[TI*LN];
  __shared__ float sCapN[LN];
  __shared__ float sImgN[TI*RN];
  __shared__ float sEt[TI*LN];
  __shared__ float sEi[TI*RN];

  const int cl = blockIdx.y;
  const int c  = cbase + cl;
  const int it = blockIdx.x;
  const int tid = threadIdx.x;
  const int nw = cap_lens[c];
  const float nwf = (float)nw;

  for (int idx = tid; idx < LN*RT/4; idx += 256) {
    const int l = idx / 36, jseg = idx - l*36;
    const float4 v = *(const float4*)(dots + ((size_t)cl*LN + l)*NT + (size_t)it*RT + jseg*4);
    float* dst = &sDots[l][jseg*4];
    dst[0]=v.x; dst[1]=v.y; dst[2]=v.z; dst[3]=v.w;
  }
  for (int idx = tid; idx < TI*RN*48/4; idx += 256)
    ((float4*)sGi4)[idx] = make_float4(0.f,0.f,0.f,0.f);
  for (int idx = tid; idx < 576; idx += 256) {
    const int rw = idx/12, mq = idx - rw*12;
    *(float4*)&sGc[rw*48 + mq*4] = *(const float4*)(gC + (size_t)c*LN*LN + rw*LN + mq*4);
  }
  if (tid < LN) sCapN[tid] = nC[c*LN + tid];
  if (tid < TI*RN) sImgN[tid] = nI[it*TI*RN + tid];
  __syncthreads();

  for (int idx = tid; idx < TI*RN*RN; idx += 256) {
    const int i = idx / (RN*RN), rem = idx - i*(RN*RN);
    const int s = rem / RN, col = rem - s*RN;
    const int blk = col / 9, cib = col - blk*9;
    sGi4[(i*RN + s)*48 + blk*12 + cib] = gI[(size_t)(it*TI+i)*RN*RN + rem];
  }
  if (tid < TI*RN) {
    const int i = tid/RN, r = tid - i*RN;
    float s = 0.f;
    for (int l = 0; l < LN; ++l) { const float v = leaky(sDots[l][i*RN+r]); s += v*v; }
    sColInv[tid] = 1.f/(sqrtf(s) + EPSF);
  }
  if (tid < TI*LN) {
    const int i = tid/LN, l = tid - i*LN;
    float s = 0.f;
    for (int r = 0; r < RN; ++r) { const float v = leaky(sDots[l][i*RN+r]); s += v*v; }
    sRowInv[tid] = 1.f/(sqrtf(s) + EPSF);
  }
  __syncthreads();

  const int team = tid >> 2, q4 = tid & 3;

  // ===== t2i =====
  #pragma unroll 1
  for (int pass = 0; pass < 3; ++pass) {
    const int rowid = pass*64 + team;
    const int i = rowid / LN, l = rowid - i*LN;
    const int cb = i*RN + q4*9;
    float d9[9], x12[12];
    #pragma unroll
    for (int j = 0; j < 9; ++j) d9[j] = sDots[l][cb + j];
    float m = -1e30f;
    #pragma unroll
    for (int j = 0; j < 9; ++j) {
      const float v = leaky(d9[j]) * sColInv[cb + j] * LSM;
      x12[j] = v; m = fmaxf(m, v);
    }
    x12[9] = x12[10] = x12[11] = -1e30f;
    m = fmaxf(m, __shfl_xor(m, 1, 4));
    m = fmaxf(m, __shfl_xor(m, 2, 4));
    float se = 0.f;
    #pragma unroll
    for (int j = 0; j < 12; ++j) { const float e = expf(x12[j] - m); x12[j] = e; se += e; }
    se += __shfl_xor(se, 1, 4); se += __shfl_xor(se, 2, 4);
    float s = 0.f;
    #pragma unroll
    for (int j = 0; j < 12; ++j) { const float p = x12[j]/se; x12[j] = p; s += p; }
    s += __shfl_xor(s, 1, 4); s += __shfl_xor(s, 2, 4);
    float ts = 0.f;
    #pragma unroll
    for (int j = 0; j < 12; ++j) {
      const float tv = (x12[j]*36.f - s > 0.f) ? x12[j] : 0.f;
      x12[j] = tv; ts += tv;
    }
    ts += __shfl_xor(ts, 1, 4); ts += __shfl_xor(ts, 2, 4);
    const float den = (ts > 0.f) ? ts : 1.f;
    float w12 = 0.f;
    #pragma unroll
    for (int j = 0; j < 9; ++j) w12 += x12[j]*d9[j];
    w12 += __shfl_xor(w12, 1, 4); w12 += __shfl_xor(w12, 2, 4);
    float qq = 0.f;
    const float* giB = sGi4 + (size_t)i*RN*48 + q4*12;
    #pragma unroll
    for (int sl = 0; sl < 4; ++sl) {
      #pragma unroll
      for (int si = 0; si < 9; ++si) {
        const float tv = __shfl(x12[si], sl, 4);
        const float4* gr = (const float4*)(giB + (sl*9 + si)*48);
        const float4 g0 = gr[0], g1 = gr[1], g2 = gr[2];
        const float p =
          x12[0]*g0.x + x12[1]*g0.y + x12[2]*g0.z + x12[3]*g0.w +
          x12[4]*g1.x + x12[5]*g1.y + x12[6]*g1.z + x12[7]*g1.w +
          x12[8]*g2.x + x12[9]*g2.y + x12[10]*g2.z + x12[11]*g2.w;
        qq += tv * p;
      }
    }
    qq += __shfl_xor(qq, 1, 4); qq += __shfl_xor(qq, 2, 4);
    if (q4 == 0) {
      const float w2 = sqrtf(fmaxf(qq/(den*den), 1e-16f));
      const float sim = (w12/den) / fmaxf(sCapN[l]*w2, EPSF);
      sEt[rowid] = (l < nw) ? expf(LLSE*sim) : 0.f;
    }
  }

  // ===== i2t =====
  #pragma unroll 1
  for (int pass = 0; pass < 3; ++pass) {
    const int rowid = pass*64 + team;
    if (rowid < TI*RN) {
      const int i = rowid / RN, r = rowid - i*RN;
      float d12[12], x12[12];
      #pragma unroll
      for (int j = 0; j < 12; ++j) d12[j] = sDots[q4*12+j][i*RN + r];
      float m = -1e30f;
      #pragma unroll
      for (int j = 0; j < 12; ++j) {
        const int l = q4*12 + j;
        const float v = (l < nw) ? leaky(d12[j]) * sRowInv[i*LN + l] * LSM : -1e9f;
        x12[j] = v; m = fmaxf(m, v);
      }
      m = fmaxf(m, __shfl_xor(m, 1, 4));
      m = fmaxf(m, __shfl_xor(m, 2, 4));
      float se = 0.f;
      #pragma unroll
      for (int j = 0; j < 12; ++j) { const float e = expf(x12[j] - m); x12[j] = e; se += e; }
      se += __shfl_xor(se, 1, 4); se += __shfl_xor(se, 2, 4);
      float s = 0.f;
      #pragma unroll
      for (int j = 0; j < 12; ++j) { const float p = x12[j]/se; x12[j] = p; s += p; }
      s += __shfl_xor(s, 1, 4); s += __shfl_xor(s, 2, 4);
      float ts = 0.f;
      #pragma unroll
      for (int j = 0; j < 12; ++j) {
        const float tv = (x12[j]*nwf - s > 0.f) ? x12[j] : 0.f;
        x12[j] = tv; ts += tv;
      }
      ts += __shfl_xor(ts, 1, 4); ts += __shfl_xor(ts, 2, 4);
      const float den = (ts > 0.f) ? ts : 1.f;
      float w12 = 0.f;
      #pragma unroll
      for (int j = 0; j < 12; ++j) w12 += x12[j]*d12[j];
      w12 += __shfl_xor(w12, 1, 4); w12 += __shfl_xor(w12, 2, 4);
      float qq = 0.f;
      const float* gcB = sGc + q4*12;
      #pragma unroll
      for (int sl = 0; sl < 4; ++sl) {
        #pragma unroll
        for (int si = 0; si < 12; ++si) {
          const float tv = __shfl(x12[si], sl, 4);
          const float4* gr = (const float4*)(gcB + (sl*12 + si)*48);
          const float4 g0 = gr[0], g1 = gr[1], g2 = gr[2];
          const float p =
            x12[0]*g0.x + x12[1]*g0.y + x12[2]*g0.z + x12[3]*g0.w +
            x12[4]*g1.x + x12[5]*g1.y + x12[6]*g1.z + x12[7]*g1.w +
            x12[8]*g2.x + x12[9]*g2.y + x12[10]*g2.z + x12[11]*g2.w;
          qq += tv * p;
        }
      }
      qq += __shfl_xor(qq, 1, 4); qq += __shfl_xor(qq, 2, 4);
      if (q4 == 0) {
        const float w2 = sqrtf(fmaxf(qq/(den*den), 1e-16f));
        const float sim = (w12/den) / fmaxf(sImgN[rowid]*w2, EPSF);
        sEi[rowid] = expf(LLSE*sim);
      }
    }
  }
  __syncthreads();
  if (tid < TI) {
    float st = 0.f, si2 = 0.f;
    for (int l = 0; l < LN; ++l) st += sEt[tid*LN + l];
    for (int r = 0; r < RN; ++r) si2 += sEi[tid*RN + r];
    scores[(size_t)(it*TI + tid)*CN + c] = logf(st)/LLSE + logf(si2)/LLSE;
  }
}

// ---------------- Kernel 4: margin ranking loss ----------------
__global__ __launch_bounds__(128) void loss_kernel(
    const float* __restrict__ S, float* __restrict__ out)
{
  __shared__ float red[128];
  const int t = threadIdx.x;
  const float d = S[t*CN + t];
  float m1 = -1e30f, m2 = -1e30f;
  for (int cc = 0; cc < CN; ++cc)
    if (cc != t) m1 = fmaxf(m1, 0.2f + S[t*CN+cc] - d);
  for (int i2 = 0; i2 < INN; ++i2)
    if (i2 != t) m2 = fmaxf(m2, 0.2f + S[i2*CN+t] - d);
  red[t] = fmaxf(m1, 0.f) + fmaxf(m2, 0.f);
  __syncthreads();
  for (int s = 64; s > 0; s >>= 1) {
    if (t < s) red[t] += red[t+s];
    __syncthreads();
  }
  if (t == 0) out[0] = red[0];
}

extern "C" void kernel_launch(void* const* d_in, const int* in_sizes, int n_in,
                              void* d_out, int out_size, void* d_ws, size_t ws_size,
                              hipStream_t stream) {
  (void)in_sizes; (void)n_in; (void)out_size;
  const float* imgs = (const float*)d_in[0];
  const float* caps = (const float*)d_in[1];
  const int*   lens = (const int*)d_in[2];

  const size_t bfUS = 2*((size_t)MT + NT)*DN;
  const size_t smallF = (size_t)INN*RN*RN + INN*RN + (size_t)CN*LN*LN + CN*LN + (size_t)INN*CN;
  int g = CN;
  while (g > 8) {
    const size_t need = bfUS*2 + (smallF + (size_t)g*LN*NT)*4;
    if (need <= ws_size) break;
    g >>= 1;
  }

  ushort* aHi = (ushort*)d_ws;
  ushort* aLo = aHi + (size_t)MT*DN;
  ushort* bHi = aLo + (size_t)MT*DN;
  ushort* bLo = bHi + (size_t)NT*DN;
  float* fbase = (float*)(bLo + (size_t)NT*DN);
  float* gI     = fbase;
  float* nI     = gI + (size_t)INN*RN*RN;
  float* gC     = nI + (size_t)INN*RN;
  float* nC     = gC + (size_t)CN*LN*LN;
  float* scores = nC + (size_t)CN*LN;
  float* dots   = scores + (size_t)INN*CN;

  conv_kernel<<<dim3(1024), dim3(256), 0, stream>>>(caps, imgs, aHi, aLo, bHi, bLo);
  gram_kernel<<<dim3(INN+CN), dim3(256), 0, stream>>>(imgs, caps, gI, nI, gC, nC);
  for (int c0 = 0; c0 < CN; c0 += g) {
    dots_gemm_mfma<<<dim3(NT/128, g*LN/128), dim3(256), 0, stream>>>(
        aHi, aLo, bHi, bLo, dots, c0*LN);
    attn_kernel<<<dim3(INN/TI, g), dim3(256), 0, stream>>>(
        dots, lens, gI, nI, gC, nC, scores, c0);
  }
  loss_kernel<<<dim3(1), dim3(128), 0, stream>>>(scores, (float*)d_out);
}